// Round 10
// baseline (368.021 us; speedup 1.0000x reference)
//
#include <hip/hip_runtime.h>
#include <hip/hip_bf16.h>

#define B_ 256
#define T_ 32
#define F_ 128
#define H_ 128
#define NF 64
#define OH 31
#define OW 255
#define POS_TOTAL (OH*OW)      // 7905
#define N1 256
#define KT 248                 // kt blocks; each owns 32 consecutive pos, all 64 filters

typedef __attribute__((ext_vector_type(8))) short bf16x8;
typedef __attribute__((ext_vector_type(4))) float f32x4;

__device__ __forceinline__ unsigned int cvtpk(float lo, float hi) {
    unsigned int r;
    asm("v_cvt_pk_bf16_f32 %0, %1, %2" : "=v"(r) : "v"(lo), "v"(hi));
    return r;
}

__device__ __forceinline__ void gll16(const void* g, void* l) {
    __builtin_amdgcn_global_load_lds(
        (const __attribute__((address_space(1))) void*)g,
        (__attribute__((address_space(3))) void*)l, 16, 0, 0);
}

// ---------------- K1: attention -> featL [b=256][rc=8192] ----------------
__global__ __launch_bounds__(256) void k_attn(
    const float* __restrict__ X, const float* __restrict__ W,
    const float* __restrict__ U, const float* __restrict__ V,
    float* __restrict__ featL)
{
    __shared__ float Xs[T_][F_];
    __shared__ float xw[T_][H_];
    __shared__ float xu[T_][H_];
    __shared__ float sc[T_][T_];
    __shared__ float Vs[H_];

    const int b = blockIdx.x;
    const int t = threadIdx.x;
    const float* Xb = X + (size_t)b * T_ * F_;

    for (int idx = t; idx < T_*F_; idx += 256) ((float*)Xs)[idx] = Xb[idx];
    if (t < H_) Vs[t] = V[t];
    __syncthreads();

    {
        const int h = t & 127, half = t >> 7;
        float aw[16], au[16];
        #pragma unroll
        for (int r = 0; r < 16; r++) { aw[r] = 0.f; au[r] = 0.f; }
        for (int f = 0; f < F_; f++) {
            const float wv = W[f*H_ + h];
            const float uv = U[f*H_ + h];
            #pragma unroll
            for (int r = 0; r < 16; r++) {
                const float xv = Xs[half*16 + r][f];
                aw[r] += xv * wv;
                au[r] += xv * uv;
            }
        }
        #pragma unroll
        for (int r = 0; r < 16; r++) {
            xw[half*16 + r][h] = aw[r];
            xu[half*16 + r][h] = au[r];
        }
    }
    __syncthreads();

    {
        const int i = t >> 3;
        const int j0 = (t & 7) * 4;
        float s0 = 0.f, s1 = 0.f, s2 = 0.f, s3 = 0.f;
        for (int h = 0; h < H_; h++) {
            const float xwv = xw[i][h];
            const float vv  = Vs[h];
            s0 += tanhf(xwv + xu[j0+0][h]) * vv;
            s1 += tanhf(xwv + xu[j0+1][h]) * vv;
            s2 += tanhf(xwv + xu[j0+2][h]) * vv;
            s3 += tanhf(xwv + xu[j0+3][h]) * vv;
        }
        sc[i][j0+0] = s0; sc[i][j0+1] = s1; sc[i][j0+2] = s2; sc[i][j0+3] = s3;
    }
    __syncthreads();

    if (t < T_) {
        float m = -1e30f;
        #pragma unroll
        for (int j = 0; j < T_; j++) m = fmaxf(m, sc[t][j]);
        float sum = 0.f;
        #pragma unroll
        for (int j = 0; j < T_; j++) sum += expf(sc[t][j] - m);
        const float inv = 1.f / sum;
        #pragma unroll
        for (int j = 0; j < T_; j++) {
            const float a = expf(sc[t][j] - m) * inv;
            sc[t][j] = (j == t) ? 0.f : a;
        }
    }
    __syncthreads();

    for (int idx = t; idx < T_*F_; idx += 256) {
        const int row = idx >> 7, f = idx & 127;
        float acc = 0.f;
        #pragma unroll
        for (int j = 0; j < T_; j++) acc += sc[row][j] * Xs[j][f];
        float* fr = featL + (size_t)b*8192 + row*256;
        fr[f]       = Xs[row][f];
        fr[128 + f] = acc;
    }
}

// -------- K1b: transpose featL[b][rc] -> featT[rc][b], LDS-tiled --------
__global__ __launch_bounds__(256) void k_tr(
    const float* __restrict__ src, float* __restrict__ dst)
{
    __shared__ float tile[32][33];
    const int rc0 = blockIdx.x * 32;
    const int b0  = blockIdx.y * 32;
    const int tx = threadIdx.x & 31;
    const int ty = threadIdx.x >> 5;
    #pragma unroll
    for (int r = 0; r < 32; r += 8)
        tile[ty + r][tx] = src[(size_t)(b0 + ty + r)*8192 + rc0 + tx];
    __syncthreads();
    #pragma unroll
    for (int r = 0; r < 32; r += 8)
        dst[(size_t)(rc0 + ty + r)*256 + b0 + tx] = tile[tx][ty + r];
}

// ------- K2: fused conv + MFMA GEMM1, deep global_load_lds pipeline -------
// Grid (2 nt, 248 kt). Tile 256m x 128n; K-step = 1 filter x 32 consecutive pos.
// w1: 6 LDS buffers, prefetch distance 4, counted vmcnt(6) (never 0 in steady
// state). Patch block-constant in registers.
__global__ __launch_bounds__(512, 2) void k_gemm1(
    const float* __restrict__ featT, const float* __restrict__ cw,
    const float* __restrict__ cb, const float* __restrict__ w1,
    float* __restrict__ partial)
{
    __shared__ float          WsL[6][16][260];   // ~100 KiB: [buf][rowpair][2*128+4]
    __shared__ unsigned short As[2][256][40];    // 40 KiB: [buf][m][k] pitch 40
    __shared__ float cwL[256];
    __shared__ float cbL[64];

    const int t  = threadIdx.x;
    const int nt = blockIdx.x;         // 0/1 n-half
    const int kt = blockIdx.y;         // 0..247
    const int nb = nt * 128;
    const int pos0 = kt * 32;

    if (t < 256) cwL[t] = cw[t];
    if (t < 64)  cbL[t] = cb[t];

    const int rm = t & 255;      // A row (batch)
    const int ph = t >> 8;       // 0/1: pos half (16 pos each)
    const int pbase = pos0 + ph*16;

    // MFMA role: 8 waves = 4(m) x 2(n); wave tile 64x64
    const int lane = t & 63, wid = t >> 6;
    const int wm = (wid & 3) * 64;
    const int wn = (wid >> 2) * 64;
    const int fr = lane & 15, fq = lane >> 4;

    f32x4 acc[4][4];
    #pragma unroll
    for (int i = 0; i < 4; i++)
        #pragma unroll
        for (int j = 0; j < 4; j++)
            acc[i][j] = (f32x4){0.f, 0.f, 0.f, 0.f};

    // ---- block-constant conv patch: 4 taps x 16 pos per thread ----
    float p0[16], p1[16], p2[16], p3[16];
    #pragma unroll
    for (int i = 0; i < 16; i++) {
        int p = pbase + i; if (p > POS_TOTAL-1) p = POS_TOTAL-1;
        const int y = p / 255, x = p - y*255;
        const float* fp = featT + ((size_t)(y*256 + x))*256 + rm;
        p0[i] = fp[0];
        p1[i] = fp[256];
        p2[i] = fp[65536];
        p3[i] = fp[65536 + 256];
    }

    // w1 DMA: wave wid covers row-pairs wid*2, wid*2+1. Per-lane source addr.
#define GLLW(F2)                                                               \
    {                                                                          \
        const int wb_ = (F2) % 6;                                              \
        _Pragma("unroll")                                                      \
        for (int j = 0; j < 2; j++) {                                          \
            const int pr_ = wid*2 + j;               /* pair 0..15 */          \
            int pos_ = pos0 + pr_*2 + (lane >> 5);                             \
            if (pos_ > POS_TOTAL-1) pos_ = POS_TOTAL-1;                        \
            gll16(w1 + ((size_t)(F2)*POS_TOTAL + pos_)*N1 + nb                 \
                     + ((lane & 31) << 2),                                     \
                  &WsL[wb_][pr_][0]);                                          \
        }                                                                      \
    }

    // conv + bf16 + ds_write: thread covers row rm, pos half ph, filter F2
#define CONVW(F2)                                                              \
    {                                                                          \
        const float4 cc_ = *(const float4*)&cwL[(F2)*4];                       \
        const float cbv_ = cbL[F2];                                            \
        unsigned int pk_[8];                                                   \
        _Pragma("unroll")                                                      \
        for (int i2 = 0; i2 < 8; i2++) {                                       \
            float v0_ = p0[2*i2]*cc_.x + p1[2*i2]*cc_.y                        \
                      + p2[2*i2]*cc_.z + p3[2*i2]*cc_.w + cbv_;                \
            float v1_ = p0[2*i2+1]*cc_.x + p1[2*i2+1]*cc_.y                    \
                      + p2[2*i2+1]*cc_.z + p3[2*i2+1]*cc_.w + cbv_;            \
            v0_ = (pbase + 2*i2     < POS_TOTAL) ? fmaxf(v0_, 0.f) : 0.f;      \
            v1_ = (pbase + 2*i2 + 1 < POS_TOTAL) ? fmaxf(v1_, 0.f) : 0.f;      \
            pk_[i2] = cvtpk(v0_, v1_);                                         \
        }                                                                      \
        *(uint4*)&As[(F2) & 1][rm][ph*16    ] = *(uint4*)&pk_[0];              \
        *(uint4*)&As[(F2) & 1][rm][ph*16 + 8] = *(uint4*)&pk_[4];              \
    }

#define LOOP_BODY(F, VMC)                                                      \
    {                                                                          \
        /* A-fragments -> regs, then As[F&1] is free after bar A */            \
        bf16x8 af_[4];                                                         \
        _Pragma("unroll")                                                      \
        for (int mg = 0; mg < 4; mg++)                                         \
            af_[mg] = *(const bf16x8*)&As[(F) & 1][wm + mg*16 + fr][fq*8];     \
        asm volatile("s_waitcnt lgkmcnt(0)" ::: "memory");                     \
        __builtin_amdgcn_s_barrier();                    /* bar A */           \
        if ((F) < 62) CONVW((F) + 2);                                          \
        {                                                                      \
            const int wb_ = (F) % 6;                                           \
            __builtin_amdgcn_s_setprio(1);                                     \
            _Pragma("unroll")                                                  \
            for (int ng = 0; ng < 4; ng++) {                                   \
                const int colb = wn + ng*16 + fr;                              \
                float w_[8];                                                   \
                _Pragma("unroll")                                              \
                for (int j = 0; j < 8; j++)                                    \
                    w_[j] = WsL[wb_][fq*4 + (j >> 1)][(j & 1)*128 + colb];     \
                bf16x8 bfr;                                                    \
                unsigned int* bu = (unsigned int*)&bfr;                        \
                _Pragma("unroll")                                              \
                for (int j2 = 0; j2 < 4; j2++)                                 \
                    bu[j2] = cvtpk(w_[2*j2], w_[2*j2+1]);                      \
                _Pragma("unroll")                                              \
                for (int mg = 0; mg < 4; mg++)                                 \
                    acc[mg][ng] = __builtin_amdgcn_mfma_f32_16x16x32_bf16(     \
                        af_[mg], bfr, acc[mg][ng], 0, 0, 0);                   \
            }                                                                  \
            __builtin_amdgcn_s_setprio(0);                                     \
        }                                                                      \
        asm volatile("s_waitcnt vmcnt(" #VMC ") lgkmcnt(0)" ::: "memory");     \
        __builtin_amdgcn_s_barrier();                    /* bar B */           \
    }

    // ---- prologue: pre-issue 4 W tiles; stage As0/As1 ----
    GLLW(0); GLLW(1); GLLW(2); GLLW(3);
    __syncthreads();           // one-time full drain: cwL/patch/Ws0..3 ready
    CONVW(0);
    CONVW(1);
    asm volatile("s_waitcnt lgkmcnt(0)" ::: "memory");
    __builtin_amdgcn_s_barrier();

    // ---- steady state: prefetch distance 4, vmcnt(6) ----
    #pragma unroll 1
    for (int f = 0; f < 60; f++) {
        GLLW(f + 4);           // issue earliest: 4 iterations of slack
        LOOP_BODY(f, 6);
    }
    // ---- tail: no new loads; conservative drains ----
    #pragma unroll 1
    for (int f = 60; f < 64; f++) {
        LOOP_BODY(f, 0);
    }

    // ---- write fp32 partial tile ----
    float* pp = partial + (size_t)kt * (256*N1) + nb;
    #pragma unroll
    for (int mg = 0; mg < 4; mg++)
        #pragma unroll
        for (int ng = 0; ng < 4; ng++) {
            const int col = wn + ng*16 + fr;
            #pragma unroll
            for (int j = 0; j < 4; j++) {
                const int row = wm + mg*16 + fq*4 + j;
                pp[(size_t)row*N1 + col] = acc[mg][ng][j];
            }
        }
#undef GLLW
#undef CONVW
#undef LOOP_BODY
}

// ------- K3: reduce partials + b1/relu + h@w2 relu + @w3 + b3 -------
__global__ __launch_bounds__(256) void k_head(
    const float* __restrict__ partial,
    const float* __restrict__ b1, const float* __restrict__ w2,
    const float* __restrict__ b2, const float* __restrict__ w3,
    const float* __restrict__ b3, float* __restrict__ out)
{
    __shared__ float h1s[256];
    __shared__ float h2s[32];
    const int b = blockIdx.x, t = threadIdx.x;

    const float* pb = partial + (size_t)b*N1 + t;
    float s0 = 0.f, s1 = 0.f, s2 = 0.f, s3 = 0.f;
    #pragma unroll 2
    for (int kt = 0; kt < KT; kt += 4) {
        s0 += pb[(size_t)(kt+0)*65536];
        s1 += pb[(size_t)(kt+1)*65536];
        s2 += pb[(size_t)(kt+2)*65536];
        s3 += pb[(size_t)(kt+3)*65536];
    }
    h1s[t] = fmaxf(b1[t] + ((s0+s1)+(s2+s3)), 0.f);
    __syncthreads();

    if (t < 32) {
        float s2v = b2[t];
        for (int i = 0; i < 256; i++) s2v += h1s[i] * w2[i*32 + t];
        h2s[t] = fmaxf(s2v, 0.f);
    }
    __syncthreads();

    if (t < 2) {
        float s3v = b3[t];
        #pragma unroll
        for (int i = 0; i < 32; i++) s3v += h2s[i] * w3[i*2 + t];
        out[b*2 + t] = s3v;
    }
}

extern "C" void kernel_launch(void* const* d_in, const int* in_sizes, int n_in,
                              void* d_out, int out_size, void* d_ws, size_t ws_size,
                              hipStream_t stream) {
    const float* X    = (const float*)d_in[0];
    const float* attW = (const float*)d_in[1];
    const float* attU = (const float*)d_in[2];
    const float* attV = (const float*)d_in[3];
    const float* cw   = (const float*)d_in[4];
    const float* cb   = (const float*)d_in[5];
    const float* w1   = (const float*)d_in[6];
    const float* b1   = (const float*)d_in[7];
    const float* w2   = (const float*)d_in[8];
    const float* b2   = (const float*)d_in[9];
    const float* w3   = (const float*)d_in[10];
    const float* b3   = (const float*)d_in[11];
    float* out = (float*)d_out;

    float* featL   = (float*)d_ws;                                   //  8 MB
    float* featT   = (float*)((char*)d_ws + (8u<<20));               //  8 MB
    float* partial = (float*)((char*)d_ws + (16u<<20));              // 62 MB

    k_attn <<<dim3(B_),       dim3(256), 0, stream>>>(X, attW, attU, attV, featL);
    k_tr   <<<dim3(256, 8),   dim3(256), 0, stream>>>(featL, featT);
    k_gemm1<<<dim3(2, KT),    dim3(512), 0, stream>>>(featT, cw, cb, w1, partial);
    k_head <<<dim3(B_),       dim3(256), 0, stream>>>(partial, b1, w2, b2, w3, b3, out);
}

// Round 11
// 269.512 us; speedup vs baseline: 1.3655x; 1.3655x over previous
//
#include <hip/hip_runtime.h>
#include <hip/hip_bf16.h>

#define B_ 256
#define T_ 32
#define F_ 128
#define H_ 128
#define NF 64
#define OH 31
#define OW 255
#define POS_TOTAL (OH*OW)      // 7905
#define N1 256
#define KT 248                 // blocks = 31 y-rows x 8 x-blocks of 32

typedef __attribute__((ext_vector_type(8))) short bf16x8;
typedef __attribute__((ext_vector_type(4))) float f32x4;

__device__ __forceinline__ unsigned int cvtpk(float lo, float hi) {
    unsigned int r;
    asm("v_cvt_pk_bf16_f32 %0, %1, %2" : "=v"(r) : "v"(lo), "v"(hi));
    return r;
}

// ---------------- K1: attention -> featL [b=256][rc=8192] ----------------
__global__ __launch_bounds__(256) void k_attn(
    const float* __restrict__ X, const float* __restrict__ W,
    const float* __restrict__ U, const float* __restrict__ V,
    float* __restrict__ featL)
{
    __shared__ float Xs[T_][F_];
    __shared__ float xw[T_][H_];
    __shared__ float xu[T_][H_];
    __shared__ float sc[T_][T_];
    __shared__ float Vs[H_];

    const int b = blockIdx.x;
    const int t = threadIdx.x;
    const float* Xb = X + (size_t)b * T_ * F_;

    for (int idx = t; idx < T_*F_; idx += 256) ((float*)Xs)[idx] = Xb[idx];
    if (t < H_) Vs[t] = V[t];
    __syncthreads();

    {
        const int h = t & 127, half = t >> 7;
        float aw[16], au[16];
        #pragma unroll
        for (int r = 0; r < 16; r++) { aw[r] = 0.f; au[r] = 0.f; }
        for (int f = 0; f < F_; f++) {
            const float wv = W[f*H_ + h];
            const float uv = U[f*H_ + h];
            #pragma unroll
            for (int r = 0; r < 16; r++) {
                const float xv = Xs[half*16 + r][f];
                aw[r] += xv * wv;
                au[r] += xv * uv;
            }
        }
        #pragma unroll
        for (int r = 0; r < 16; r++) {
            xw[half*16 + r][h] = aw[r];
            xu[half*16 + r][h] = au[r];
        }
    }
    __syncthreads();

    {
        const int i = t >> 3;
        const int j0 = (t & 7) * 4;
        float s0 = 0.f, s1 = 0.f, s2 = 0.f, s3 = 0.f;
        for (int h = 0; h < H_; h++) {
            const float xwv = xw[i][h];
            const float vv  = Vs[h];
            s0 += tanhf(xwv + xu[j0+0][h]) * vv;
            s1 += tanhf(xwv + xu[j0+1][h]) * vv;
            s2 += tanhf(xwv + xu[j0+2][h]) * vv;
            s3 += tanhf(xwv + xu[j0+3][h]) * vv;
        }
        sc[i][j0+0] = s0; sc[i][j0+1] = s1; sc[i][j0+2] = s2; sc[i][j0+3] = s3;
    }
    __syncthreads();

    if (t < T_) {
        float m = -1e30f;
        #pragma unroll
        for (int j = 0; j < T_; j++) m = fmaxf(m, sc[t][j]);
        float sum = 0.f;
        #pragma unroll
        for (int j = 0; j < T_; j++) sum += expf(sc[t][j] - m);
        const float inv = 1.f / sum;
        #pragma unroll
        for (int j = 0; j < T_; j++) {
            const float a = expf(sc[t][j] - m) * inv;
            sc[t][j] = (j == t) ? 0.f : a;
        }
    }
    __syncthreads();

    for (int idx = t; idx < T_*F_; idx += 256) {
        const int row = idx >> 7, f = idx & 127;
        float acc = 0.f;
        #pragma unroll
        for (int j = 0; j < T_; j++) acc += sc[row][j] * Xs[j][f];
        float* fr = featL + (size_t)b*8192 + row*256;
        fr[f]       = Xs[row][f];
        fr[128 + f] = acc;
    }
}

// -------- K1b: transpose featL[b][rc] -> featT[rc][b], LDS-tiled --------
__global__ __launch_bounds__(256) void k_tr(
    const float* __restrict__ src, float* __restrict__ dst)
{
    __shared__ float tile[32][33];
    const int rc0 = blockIdx.x * 32;
    const int b0  = blockIdx.y * 32;
    const int tx = threadIdx.x & 31;
    const int ty = threadIdx.x >> 5;
    #pragma unroll
    for (int r = 0; r < 32; r += 8)
        tile[ty + r][tx] = src[(size_t)(b0 + ty + r)*8192 + rc0 + tx];
    __syncthreads();
    #pragma unroll
    for (int r = 0; r < 32; r += 8)
        dst[(size_t)(rc0 + ty + r)*256 + b0 + tx] = tile[tx][ty + r];
}

// ------- K2: fused conv + MFMA GEMM1 — 32 fat steps, 1 barrier each -------
// Grid 248 = (y = kt>>3, xb = kt&7): block owns pos window y*255 + [xb*32, +32)
// (width 31 for xb=7), all 64 filters. Step s: K=64 = filters {2s,2s+1} x 32 pos.
// LDS 128 KiB: As/Ws bf16 [buf][256][64], XOR-block swizzle (blk ^= row&7).
__global__ __launch_bounds__(512, 2) void k_gemm1(
    const float* __restrict__ featT, const float* __restrict__ cw,
    const float* __restrict__ cb, const float* __restrict__ w1,
    float* __restrict__ partial)
{
    __shared__ unsigned short As[2][256*64];   // 2 x 32 KiB
    __shared__ unsigned short Ws[2][256*64];   // 2 x 32 KiB
    __shared__ float cwL[256];
    __shared__ float cbL[64];

    const int t  = threadIdx.x;
    const int kt = blockIdx.x;
    const int y  = kt >> 3;
    const int x0 = (kt & 7) * 32;

    if (t < 256) cwL[t] = cw[t];
    if (t < 64)  cbL[t] = cb[t];

    // A-staging role: row rm, pos-half ph (16 pos each)
    const int rm = t & 255;
    const int ph = t >> 8;
    // W-staging role: 4 k-rows x 8 n-cols
    const int r0 = (t & 15) * 4;        // k-local 0..60
    const int c0 = (t >> 4) * 8;        // n 0..248
    // MFMA role: 8 waves = 2(m) x 4(n); wave tile 128x64
    const int lane = t & 63, wid = t >> 6;
    const int wm = (wid >> 2) * 128;
    const int wn = (wid & 3) * 64;
    const int fr = lane & 15, fq = lane >> 4;

    f32x4 acc[8][4];
    #pragma unroll
    for (int i = 0; i < 8; i++)
        #pragma unroll
        for (int j = 0; j < 4; j++)
            acc[i][j] = (f32x4){0.f, 0.f, 0.f, 0.f};

    // ---- block-constant conv patch: overlapping taps -> 2x17 regs ----
    float topv[17], botv[17];
    #pragma unroll
    for (int i = 0; i < 17; i++) {
        int xc = x0 + ph*16 + i; if (xc > 255) xc = 255;
        topv[i] = featT[((size_t)(y*256 + xc))*256 + rm];
        botv[i] = featT[((size_t)((y+1)*256 + xc))*256 + rm];
    }

    float wvf[4][8];   // W stage regs: [k-row jj][n-col i]

    // W loads for step S: rows r0..r0+3 (k-local), cols c0..c0+7, coalesced float4
#define W_LOADS(S)                                                             \
    {                                                                          \
        const int fl_ = r0 >> 5;                                               \
        const int f_  = 2*(S) + fl_;                                           \
        _Pragma("unroll")                                                      \
        for (int jj = 0; jj < 4; jj++) {                                       \
            int xc_ = x0 + (r0 & 31) + jj; if (xc_ > 254) xc_ = 254;           \
            const float* wp_ = w1 + ((size_t)(f_*POS_TOTAL + y*255 + xc_))*N1  \
                                  + c0;                                        \
            *(float4*)&wvf[jj][0] = *(const float4*)&wp_[0];                   \
            *(float4*)&wvf[jj][4] = *(const float4*)&wp_[4];                   \
        }                                                                      \
    }

    // stage step S into buffer BUF: W transpose-write + conv A
#define STAGE(BUF, S)                                                          \
    {                                                                          \
        _Pragma("unroll")                                                      \
        for (int i = 0; i < 8; i++) {                                          \
            const int n_ = c0 + i;                                             \
            uint2 v_;                                                          \
            v_.x = cvtpk(wvf[0][i], wvf[1][i]);                                \
            v_.y = cvtpk(wvf[2][i], wvf[3][i]);                                \
            const int blk_ = (r0 >> 3) ^ (n_ & 7);                             \
            *(uint2*)&Ws[BUF][n_*64 + blk_*8 + (r0 & 7)] = v_;                 \
        }                                                                      \
        _Pragma("unroll")                                                      \
        for (int fl = 0; fl < 2; fl++) {                                       \
            const int f_ = 2*(S) + fl;                                         \
            const float4 cc_ = *(const float4*)&cwL[f_*4];                     \
            const float cbv_ = cbL[f_];                                        \
            unsigned int pk_[4];                                               \
            _Pragma("unroll")                                                  \
            for (int i2 = 0; i2 < 8; i2++) {                                   \
                const int i0 = 2*i2, i1 = 2*i2 + 1;                            \
                float v0_ = topv[i0]*cc_.x + topv[i0+1]*cc_.y                  \
                          + botv[i0]*cc_.z + botv[i0+1]*cc_.w + cbv_;          \
                float v1_ = topv[i1]*cc_.x + topv[i1+1]*cc_.y                  \
                          + botv[i1]*cc_.z + botv[i1+1]*cc_.w + cbv_;          \
                v0_ = (x0 + ph*16 + i0 < 255) ? fmaxf(v0_, 0.f) : 0.f;         \
                v1_ = (x0 + ph*16 + i1 < 255) ? fmaxf(v1_, 0.f) : 0.f;         \
                pk_[i2 & 3] = cvtpk(v0_, v1_);                                 \
                if ((i2 & 3) == 3) {                                           \
                    const int kb_ = fl*4 + ph*2 + (i2 >> 2);                   \
                    *(uint4*)&As[BUF][rm*64 + ((kb_ ^ (rm & 7))*8)]            \
                        = *(uint4*)&pk_[0];                                    \
                }                                                              \
            }                                                                  \
        }                                                                      \
    }

    // ---- prologue ----
    W_LOADS(0);
    __syncthreads();             // cwL/cbL/patch/wvf visible (one-time drain)
    STAGE(0, 0);
    asm volatile("s_waitcnt lgkmcnt(0)" ::: "memory");
    __builtin_amdgcn_s_barrier();

    #pragma unroll 1
    for (int s = 0; s < 32; s++) {
        const int cur = s & 1;
        if (s < 31) W_LOADS(s + 1);          // issue early; lands under MFMA

        __builtin_amdgcn_s_setprio(1);
        #pragma unroll
        for (int kc = 0; kc < 2; kc++) {
            const int sw = ((kc*4 + fq) ^ (fr & 7)) * 8;
            bf16x8 bf_[4];
            #pragma unroll
            for (int ng = 0; ng < 4; ng++)
                bf_[ng] = *(const bf16x8*)&Ws[cur][(wn + ng*16 + fr)*64 + sw];
            #pragma unroll
            for (int mg = 0; mg < 8; mg++) {
                const bf16x8 af_ =
                    *(const bf16x8*)&As[cur][(wm + mg*16 + fr)*64 + sw];
                #pragma unroll
                for (int ng = 0; ng < 4; ng++)
                    acc[mg][ng] = __builtin_amdgcn_mfma_f32_16x16x32_bf16(
                        af_, bf_[ng], acc[mg][ng], 0, 0, 0);
            }
        }
        __builtin_amdgcn_s_setprio(0);

        if (s < 31) STAGE(cur ^ 1, s + 1);   // auto-vmcnt on wvf use
        asm volatile("s_waitcnt lgkmcnt(0)" ::: "memory");
        __builtin_amdgcn_s_barrier();
    }

    // ---- write fp32 partial tile (256x256) ----
    float* pp = partial + (size_t)kt * (256*N1);
    #pragma unroll
    for (int mg = 0; mg < 8; mg++)
        #pragma unroll
        for (int ng = 0; ng < 4; ng++) {
            const int col = wn + ng*16 + fr;
            #pragma unroll
            for (int j = 0; j < 4; j++) {
                const int row = wm + mg*16 + fq*4 + j;
                pp[(size_t)row*N1 + col] = acc[mg][ng][j];
            }
        }
#undef W_LOADS
#undef STAGE
}

// ------- K3: reduce partials + b1/relu + h@w2 relu + @w3 + b3 -------
__global__ __launch_bounds__(256) void k_head(
    const float* __restrict__ partial,
    const float* __restrict__ b1, const float* __restrict__ w2,
    const float* __restrict__ b2, const float* __restrict__ w3,
    const float* __restrict__ b3, float* __restrict__ out)
{
    __shared__ float h1s[256];
    __shared__ float h2s[32];
    const int b = blockIdx.x, t = threadIdx.x;

    const float* pb = partial + (size_t)b*N1 + t;
    float s0 = 0.f, s1 = 0.f, s2 = 0.f, s3 = 0.f;
    #pragma unroll 2
    for (int kt = 0; kt < KT; kt += 4) {
        s0 += pb[(size_t)(kt+0)*65536];
        s1 += pb[(size_t)(kt+1)*65536];
        s2 += pb[(size_t)(kt+2)*65536];
        s3 += pb[(size_t)(kt+3)*65536];
    }
    h1s[t] = fmaxf(b1[t] + ((s0+s1)+(s2+s3)), 0.f);
    __syncthreads();

    if (t < 32) {
        float s2v = b2[t];
        for (int i = 0; i < 256; i++) s2v += h1s[i] * w2[i*32 + t];
        h2s[t] = fmaxf(s2v, 0.f);
    }
    __syncthreads();

    if (t < 2) {
        float s3v = b3[t];
        #pragma unroll
        for (int i = 0; i < 32; i++) s3v += h2s[i] * w3[i*2 + t];
        out[b*2 + t] = s3v;
    }
}

extern "C" void kernel_launch(void* const* d_in, const int* in_sizes, int n_in,
                              void* d_out, int out_size, void* d_ws, size_t ws_size,
                              hipStream_t stream) {
    const float* X    = (const float*)d_in[0];
    const float* attW = (const float*)d_in[1];
    const float* attU = (const float*)d_in[2];
    const float* attV = (const float*)d_in[3];
    const float* cw   = (const float*)d_in[4];
    const float* cb   = (const float*)d_in[5];
    const float* w1   = (const float*)d_in[6];
    const float* b1   = (const float*)d_in[7];
    const float* w2   = (const float*)d_in[8];
    const float* b2   = (const float*)d_in[9];
    const float* w3   = (const float*)d_in[10];
    const float* b3   = (const float*)d_in[11];
    float* out = (float*)d_out;

    float* featL   = (float*)d_ws;                                   //  8 MB
    float* featT   = (float*)((char*)d_ws + (8u<<20));               //  8 MB
    float* partial = (float*)((char*)d_ws + (16u<<20));              // 62 MB

    k_attn <<<dim3(B_),       dim3(256), 0, stream>>>(X, attW, attU, attV, featL);
    k_tr   <<<dim3(256, 8),   dim3(256), 0, stream>>>(featL, featT);
    k_gemm1<<<dim3(KT),       dim3(512), 0, stream>>>(featT, cw, cb, w1, partial);
    k_head <<<dim3(B_),       dim3(256), 0, stream>>>(partial, b1, w2, b2, w3, b3, out);
}

// Round 12
// 261.088 us; speedup vs baseline: 1.4096x; 1.0323x over previous
//
#include <hip/hip_runtime.h>
#include <hip/hip_bf16.h>

#define B_ 256
#define T_ 32
#define F_ 128
#define H_ 128
#define NF 64
#define OH 31
#define OW 255
#define POS_TOTAL (OH*OW)      // 7905
#define N1 256
#define KT 248                 // blocks = 31 y-rows x 8 x-blocks of 32

typedef __attribute__((ext_vector_type(8))) short bf16x8;
typedef __attribute__((ext_vector_type(4))) float f32x4;

__device__ __forceinline__ unsigned int cvtpk(float lo, float hi) {
    unsigned int r;
    asm("v_cvt_pk_bf16_f32 %0, %1, %2" : "=v"(r) : "v"(lo), "v"(hi));
    return r;
}

// ---------------- K1: attention -> featL [b=256][rc=8192] ----------------
__global__ __launch_bounds__(256) void k_attn(
    const float* __restrict__ X, const float* __restrict__ W,
    const float* __restrict__ U, const float* __restrict__ V,
    float* __restrict__ featL)
{
    __shared__ float Xs[T_][F_];
    __shared__ float xw[T_][H_];
    __shared__ float xu[T_][H_];
    __shared__ float sc[T_][T_];
    __shared__ float Vs[H_];

    const int b = blockIdx.x;
    const int t = threadIdx.x;
    const float* Xb = X + (size_t)b * T_ * F_;

    for (int idx = t; idx < T_*F_; idx += 256) ((float*)Xs)[idx] = Xb[idx];
    if (t < H_) Vs[t] = V[t];
    __syncthreads();

    {
        const int h = t & 127, half = t >> 7;
        float aw[16], au[16];
        #pragma unroll
        for (int r = 0; r < 16; r++) { aw[r] = 0.f; au[r] = 0.f; }
        for (int f = 0; f < F_; f++) {
            const float wv = W[f*H_ + h];
            const float uv = U[f*H_ + h];
            #pragma unroll
            for (int r = 0; r < 16; r++) {
                const float xv = Xs[half*16 + r][f];
                aw[r] += xv * wv;
                au[r] += xv * uv;
            }
        }
        #pragma unroll
        for (int r = 0; r < 16; r++) {
            xw[half*16 + r][h] = aw[r];
            xu[half*16 + r][h] = au[r];
        }
    }
    __syncthreads();

    {
        const int i = t >> 3;
        const int j0 = (t & 7) * 4;
        float s0 = 0.f, s1 = 0.f, s2 = 0.f, s3 = 0.f;
        for (int h = 0; h < H_; h++) {
            const float xwv = xw[i][h];
            const float vv  = Vs[h];
            s0 += tanhf(xwv + xu[j0+0][h]) * vv;
            s1 += tanhf(xwv + xu[j0+1][h]) * vv;
            s2 += tanhf(xwv + xu[j0+2][h]) * vv;
            s3 += tanhf(xwv + xu[j0+3][h]) * vv;
        }
        sc[i][j0+0] = s0; sc[i][j0+1] = s1; sc[i][j0+2] = s2; sc[i][j0+3] = s3;
    }
    __syncthreads();

    if (t < T_) {
        float m = -1e30f;
        #pragma unroll
        for (int j = 0; j < T_; j++) m = fmaxf(m, sc[t][j]);
        float sum = 0.f;
        #pragma unroll
        for (int j = 0; j < T_; j++) sum += expf(sc[t][j] - m);
        const float inv = 1.f / sum;
        #pragma unroll
        for (int j = 0; j < T_; j++) {
            const float a = expf(sc[t][j] - m) * inv;
            sc[t][j] = (j == t) ? 0.f : a;
        }
    }
    __syncthreads();

    for (int idx = t; idx < T_*F_; idx += 256) {
        const int row = idx >> 7, f = idx & 127;
        float acc = 0.f;
        #pragma unroll
        for (int j = 0; j < T_; j++) acc += sc[row][j] * Xs[j][f];
        float* fr = featL + (size_t)b*8192 + row*256;
        fr[f]       = Xs[row][f];
        fr[128 + f] = acc;
    }
}

// -------- K1b: transpose featL[b][rc] -> featT[rc][b], LDS-tiled --------
__global__ __launch_bounds__(256) void k_tr(
    const float* __restrict__ src, float* __restrict__ dst)
{
    __shared__ float tile[32][33];
    const int rc0 = blockIdx.x * 32;
    const int b0  = blockIdx.y * 32;
    const int tx = threadIdx.x & 31;
    const int ty = threadIdx.x >> 5;
    #pragma unroll
    for (int r = 0; r < 32; r += 8)
        tile[ty + r][tx] = src[(size_t)(b0 + ty + r)*8192 + rc0 + tx];
    __syncthreads();
    #pragma unroll
    for (int r = 0; r < 32; r += 8)
        dst[(size_t)(rc0 + ty + r)*256 + b0 + tx] = tile[tx][ty + r];
}

// ------- K2: fused conv + MFMA GEMM1 — W direct-to-register, 1-step slack -------
// Grid 248 = (y = kt>>3, xb = kt&7). Tile 256x256, 32 steps of K=64 (2 filters
// x 32 pos). Waves: 1m x 8n (wave tile 256x32) -> each wave loads its own
// B-fragments global->VGPR (w1 fetched once, no Ws LDS). As only in LDS
// (2 x 32 KiB, XOR-swizzled). One lgkm-only barrier per step.
__global__ __launch_bounds__(512, 2) void k_gemm1(
    const float* __restrict__ featT, const float* __restrict__ cw,
    const float* __restrict__ cb, const float* __restrict__ w1,
    float* __restrict__ partial)
{
    __shared__ unsigned short As[2][256*64];   // 2 x 32 KiB
    __shared__ float cwL[256];
    __shared__ float cbL[64];

    const int t  = threadIdx.x;
    const int kt = blockIdx.x;
    const int y  = kt >> 3;
    const int x0 = (kt & 7) * 32;

    if (t < 256) cwL[t] = cw[t];
    if (t < 64)  cbL[t] = cb[t];

    // A-staging role: row rm, pos-half ph (16 pos each)
    const int rm = t & 255;
    const int ph = t >> 8;
    // MFMA role: 8 waves, 1m x 8n; wave tile 256x32
    const int lane = t & 63, wid = t >> 6;
    const int wn = wid * 32;
    const int fr = lane & 15, fq = lane >> 4;

    f32x4 acc[16][2];
    #pragma unroll
    for (int i = 0; i < 16; i++) {
        acc[i][0] = (f32x4){0.f, 0.f, 0.f, 0.f};
        acc[i][1] = (f32x4){0.f, 0.f, 0.f, 0.f};
    }

    // ---- block-constant conv patch: overlapping taps -> 2x17 regs ----
    float topv[17], botv[17];
    #pragma unroll
    for (int i = 0; i < 17; i++) {
        int xc = x0 + ph*16 + i; if (xc > 255) xc = 255;
        topv[i] = featT[((size_t)(y*256 + xc))*256 + rm];
        botv[i] = featT[((size_t)((y+1)*256 + xc))*256 + rm];
    }

    // ---- per-lane w1 byte-offset bases (int), one per j ----
    int poff[8];
    #pragma unroll
    for (int j = 0; j < 8; j++) {
        int xc = x0 + fq*8 + j; if (xc > 254) xc = 254;   // clamped; A=0 kills it
        poff[j] = (y*255 + xc)*N1 + wn + fr;
    }

    float wv[2][2][8];   // [kc=filter][ng][j] — single set, reissued each step

    // W loads for step S (filters 2S, 2S+1), per-lane addresses
#define WLOAD(S)                                                               \
    {                                                                          \
        _Pragma("unroll")                                                      \
        for (int kc = 0; kc < 2; kc++) {                                       \
            const float* wf_ = w1 + (size_t)(2*(S) + kc) * (POS_TOTAL*N1);     \
            _Pragma("unroll")                                                  \
            for (int ng = 0; ng < 2; ng++)                                     \
                _Pragma("unroll")                                              \
                for (int j = 0; j < 8; j++)                                    \
                    wv[kc][ng][j] = wf_[poff[j] + ng*16];                      \
        }                                                                      \
    }

    // conv + bf16 + ds_write for step S into buffer BUF (2 filters)
#define STAGE(BUF, S)                                                          \
    {                                                                          \
        _Pragma("unroll")                                                      \
        for (int fl = 0; fl < 2; fl++) {                                       \
            const int f_ = 2*(S) + fl;                                         \
            const float4 cc_ = *(const float4*)&cwL[f_*4];                     \
            const float cbv_ = cbL[f_];                                        \
            unsigned int pk_[4];                                               \
            _Pragma("unroll")                                                  \
            for (int i2 = 0; i2 < 8; i2++) {                                   \
                const int i0 = 2*i2, i1 = 2*i2 + 1;                            \
                float v0_ = topv[i0]*cc_.x + topv[i0+1]*cc_.y                  \
                          + botv[i0]*cc_.z + botv[i0+1]*cc_.w + cbv_;          \
                float v1_ = topv[i1]*cc_.x + topv[i1+1]*cc_.y                  \
                          + botv[i1]*cc_.z + botv[i1+1]*cc_.w + cbv_;          \
                v0_ = (x0 + ph*16 + i0 < 255) ? fmaxf(v0_, 0.f) : 0.f;         \
                v1_ = (x0 + ph*16 + i1 < 255) ? fmaxf(v1_, 0.f) : 0.f;         \
                pk_[i2 & 3] = cvtpk(v0_, v1_);                                 \
                if ((i2 & 3) == 3) {                                           \
                    const int kb_ = fl*4 + ph*2 + (i2 >> 2);                   \
                    *(uint4*)&As[BUF][rm*64 + ((kb_ ^ (rm & 7))*8)]            \
                        = *(uint4*)&pk_[0];                                    \
                }                                                              \
            }                                                                  \
        }                                                                      \
    }

    // ---- prologue ----
    WLOAD(0);
    __syncthreads();             // one-time full drain: cwL/cbL/patch/wv0 ready
    STAGE(0, 0);
    asm volatile("s_waitcnt lgkmcnt(0)" ::: "memory");
    __builtin_amdgcn_s_barrier();

    #pragma unroll 1
    for (int s = 0; s < 32; s++) {
        const int cur = s & 1;

        // convert W set(s) (issued a full step ago) -> bf16 frags
        bf16x8 bf[2][2];
        #pragma unroll
        for (int kc = 0; kc < 2; kc++)
            #pragma unroll
            for (int ng = 0; ng < 2; ng++) {
                unsigned int* bu = (unsigned int*)&bf[kc][ng];
                #pragma unroll
                for (int q = 0; q < 4; q++)
                    bu[q] = cvtpk(wv[kc][ng][2*q], wv[kc][ng][2*q+1]);
            }

        if (s < 31) WLOAD(s + 1);       // reissue freed regs; lands next step

        __builtin_amdgcn_s_setprio(1);
        #pragma unroll
        for (int kc = 0; kc < 2; kc++) {
            const int sw = ((kc*4 + fq) ^ (fr & 7)) * 8;
            #pragma unroll
            for (int mg = 0; mg < 16; mg++) {
                const bf16x8 af =
                    *(const bf16x8*)&As[cur][(mg*16 + fr)*64 + sw];
                acc[mg][0] = __builtin_amdgcn_mfma_f32_16x16x32_bf16(
                    af, bf[kc][0], acc[mg][0], 0, 0, 0);
                acc[mg][1] = __builtin_amdgcn_mfma_f32_16x16x32_bf16(
                    af, bf[kc][1], acc[mg][1], 0, 0, 0);
            }
        }
        __builtin_amdgcn_s_setprio(0);

        if (s < 31) STAGE(cur ^ 1, s + 1);
        asm volatile("s_waitcnt lgkmcnt(0)" ::: "memory");
        __builtin_amdgcn_s_barrier();
    }

    // ---- write fp32 partial tile (256x256) ----
    float* pp = partial + (size_t)kt * (256*N1);
    #pragma unroll
    for (int mg = 0; mg < 16; mg++)
        #pragma unroll
        for (int ng = 0; ng < 2; ng++) {
            const int col = wn + ng*16 + fr;
            #pragma unroll
            for (int j = 0; j < 4; j++) {
                const int row = mg*16 + fq*4 + j;
                pp[(size_t)row*N1 + col] = acc[mg][ng][j];
            }
        }
#undef WLOAD
#undef STAGE
}

// ------- K3: reduce partials + b1/relu + h@w2 relu + @w3 + b3 -------
__global__ __launch_bounds__(256) void k_head(
    const float* __restrict__ partial,
    const float* __restrict__ b1, const float* __restrict__ w2,
    const float* __restrict__ b2, const float* __restrict__ w3,
    const float* __restrict__ b3, float* __restrict__ out)
{
    __shared__ float h1s[256];
    __shared__ float h2s[32];
    const int b = blockIdx.x, t = threadIdx.x;

    const float* pb = partial + (size_t)b*N1 + t;
    float s0 = 0.f, s1 = 0.f, s2 = 0.f, s3 = 0.f;
    #pragma unroll 2
    for (int kt = 0; kt < KT; kt += 4) {
        s0 += pb[(size_t)(kt+0)*65536];
        s1 += pb[(size_t)(kt+1)*65536];
        s2 += pb[(size_t)(kt+2)*65536];
        s3 += pb[(size_t)(kt+3)*65536];
    }
    h1s[t] = fmaxf(b1[t] + ((s0+s1)+(s2+s3)), 0.f);
    __syncthreads();

    if (t < 32) {
        float s2v = b2[t];
        for (int i = 0; i < 256; i++) s2v += h1s[i] * w2[i*32 + t];
        h2s[t] = fmaxf(s2v, 0.f);
    }
    __syncthreads();

    if (t < 2) {
        float s3v = b3[t];
        #pragma unroll
        for (int i = 0; i < 32; i++) s3v += h2s[i] * w3[i*2 + t];
        out[b*2 + t] = s3v;
    }
}

extern "C" void kernel_launch(void* const* d_in, const int* in_sizes, int n_in,
                              void* d_out, int out_size, void* d_ws, size_t ws_size,
                              hipStream_t stream) {
    const float* X    = (const float*)d_in[0];
    const float* attW = (const float*)d_in[1];
    const float* attU = (const float*)d_in[2];
    const float* attV = (const float*)d_in[3];
    const float* cw   = (const float*)d_in[4];
    const float* cb   = (const float*)d_in[5];
    const float* w1   = (const float*)d_in[6];
    const float* b1   = (const float*)d_in[7];
    const float* w2   = (const float*)d_in[8];
    const float* b2   = (const float*)d_in[9];
    const float* w3   = (const float*)d_in[10];
    const float* b3   = (const float*)d_in[11];
    float* out = (float*)d_out;

    float* featL   = (float*)d_ws;                                   //  8 MB
    float* featT   = (float*)((char*)d_ws + (8u<<20));               //  8 MB
    float* partial = (float*)((char*)d_ws + (16u<<20));              // 62 MB

    k_attn <<<dim3(B_),       dim3(256), 0, stream>>>(X, attW, attU, attV, featL);
    k_tr   <<<dim3(256, 8),   dim3(256), 0, stream>>>(featL, featT);
    k_gemm1<<<dim3(KT),       dim3(512), 0, stream>>>(featT, cw, cb, w1, partial);
    k_head <<<dim3(B_),       dim3(256), 0, stream>>>(partial, b1, w2, b2, w3, b3, out);
}